// Round 14
// baseline (163.128 us; speedup 1.0000x reference)
//
#include <hip/hip_runtime.h>

#define N_NODES    50000
#define N_EDGES    625000
#define HIDDEN     128
#define NUM_GRAPHS 128
#define EPS_GN     1e-5f
#define FIXSCALE32 65536.0f     // 2^16 fixed point, weight sum in low 24 bits
#define NSPLIT     25000        // node split for the two pipeline halves
#define NGEMM_BLK  782          // (N_NODES + 63) / 64
#define NHIST_BLK  306          // ceil(N_EDGES/8/256)
#define NCSR_BLK   611          // ceil(N_EDGES/4/256)
#define NB_HALF    98           // ceil(25000/256)
#define NGATH_BLK  1563         // ceil(25000/16)

typedef __bf16 bf16x8 __attribute__((ext_vector_type(8)));
typedef float  f32x4  __attribute__((ext_vector_type(4)));
typedef unsigned short u16x8 __attribute__((ext_vector_type(8)));
typedef unsigned long long u64;

__device__ inline unsigned short f2b(float f) {
    __bf16 b = (__bf16)f;
    return __builtin_bit_cast(unsigned short, b);
}
__device__ inline float b2f(unsigned short u) {
    unsigned int x = ((unsigned int)u) << 16;
    return __builtin_bit_cast(float, x);
}

// ---- workspace layout (4B units) ----
#define HB_OFF     0          // ushort[6,400,000] -> 3,200,000 units
#define CNT_OFF    3200000    // u32[50,000] packed cnt|wsum
#define DONE_OFF   3250000    // u32[2]
#define BSUMA_OFF  3250008    // u32[128]
#define BSUMB_OFF  3250136    // u32[128]
#define DINV_OFF   3250264    // f32[50,000]
#define WB_OFF     3300264    // u16[16,384] -> 8,192 units
#define GSTART_OFF 3308456    // int[129]
#define ROWS_OFF   3308585    // int[50,001]
#define EPACK_OFF  3358586    // u64[625,000] (even) -> 1,250,000 units
#define SLOT_OFF   4608588    // u32[625,000] (16B-aligned)
#define TMP_OFF    5233588    // u16[6,400,000] (16B-aligned) -> 3,200,000 units
// end 8,433,588 * 4B = 33.7 MB (ws is ~268 MB)

// ---------------- prep: zero cnt+done + convert W -> bf16 ----------------
__global__ void prep(const float* __restrict__ W, unsigned short* __restrict__ wb,
                     uint4* __restrict__ z) {
    int i = blockIdx.x * 256 + threadIdx.x;
    if (i < 12502) z[i] = make_uint4(0u, 0u, 0u, 0u);   // CNT[50000] + DONE[2] (+pad)
    if (i < HIDDEN * HIDDEN) wb[i] = f2b(W[i]);
}

// ---------------- histogram pass body (predicated on dst half) ----------------
__device__ inline void hist_pass(int blk, const int* __restrict__ dst,
                                 const float* __restrict__ w,
                                 unsigned int* __restrict__ cnt32,
                                 unsigned int* __restrict__ slot, bool isA) {
    int base = blk * 256 + threadIdx.x;
    if (base * 8 >= N_EDGES) return;
    int4   d0 = ((const int4*)dst)[base * 2];
    int4   d1 = ((const int4*)dst)[base * 2 + 1];
    float4 w0 = ((const float4*)w)[base * 2];
    float4 w1 = ((const float4*)w)[base * 2 + 1];
    int e0 = base * 8;
#define HPROC(EI, DV, WV)                                                        \
    if (((DV) < NSPLIT) == isA) {                                                \
        unsigned int fx = (unsigned int)((WV) * FIXSCALE32 + 0.5f);              \
        slot[EI] = atomicAdd(&cnt32[DV], (1u << 24) | fx) >> 24;                 \
    }
    HPROC(e0 + 0, d0.x, w0.x) HPROC(e0 + 1, d0.y, w0.y)
    HPROC(e0 + 2, d0.z, w0.z) HPROC(e0 + 3, d0.w, w0.w)
    HPROC(e0 + 4, d1.x, w1.x) HPROC(e0 + 5, d1.y, w1.y)
    HPROC(e0 + 6, d1.z, w1.z) HPROC(e0 + 7, d1.w, w1.w)
#undef HPROC
}

// ---------------- scan half body: dinv + gstart + rowstart over [nbase, nbase+25000) ----------------
__device__ inline void scan_half(int sbid, int nbase,
                                 const unsigned int* __restrict__ cnt32,
                                 unsigned int* __restrict__ bsum,
                                 unsigned int* __restrict__ done,
                                 float* __restrict__ dinv,
                                 const int* __restrict__ batch,
                                 int* __restrict__ gstart,
                                 int* __restrict__ rowstart) {
    __shared__ int red[256];
    __shared__ int sb[128];
    __shared__ int s[256];
    const int t = threadIdx.x;
    const int i = nbase + sbid * 256 + t;
    const int iend = nbase + NSPLIT;
    int c = 0;
    if (i < iend) {
        unsigned int v = cnt32[i];
        c = (int)(v >> 24);
        dinv[i] = rsqrtf(1.0f + (float)(v & 0xFFFFFFu) * (1.0f / FIXSCALE32));
        int b0 = batch[i];
        int prev = (i == 0) ? -1 : batch[i - 1];
        for (int g = prev + 1; g <= b0; ++g) gstart[g] = i;
        if (i == N_NODES - 1) {
            for (int g = b0 + 1; g <= NUM_GRAPHS; ++g) gstart[g] = N_NODES;
        }
    }
    red[t] = c;
    __syncthreads();
    for (int off = 128; off > 0; off >>= 1) {
        if (t < off) red[t] += red[t + off];
        __syncthreads();
    }
    if (t == 0) {
        atomicExch(&bsum[sbid], (unsigned int)red[0]);
        __threadfence();
        atomicAdd(done, 1u);
        while (atomicAdd(done, 0u) < (unsigned int)NB_HALF) {
            __builtin_amdgcn_s_sleep(2);
        }
    }
    __syncthreads();
    if (t < NB_HALF) sb[t] = (int)atomicAdd(&bsum[t], 0u);
    __syncthreads();
    // serial-ish inclusive scan of 98 values by thread 0 (tiny)
    if (t == 0) {
        int acc = 0;
        for (int k = 0; k < NB_HALF; ++k) { acc += sb[k]; sb[k] = acc; }
    }
    __syncthreads();
    int ebase = (nbase == 0) ? 0 : rowstart[nbase];   // EA written by scanA (prior dispatch)
    int boff = ebase + ((sbid == 0) ? 0 : sb[sbid - 1]);
    s[t] = c;
    __syncthreads();
    for (int off = 1; off < 256; off <<= 1) {
        int v = (t >= off) ? s[t - off] : 0;
        __syncthreads();
        s[t] += v;
        __syncthreads();
    }
    if (i < iend) rowstart[i] = boff + s[t] - c;
    if (sbid == NB_HALF - 1 && t == 0) {
        if (nbase == 0) rowstart[NSPLIT] = sb[NB_HALF - 1];       // EA (re-written by scanB, same value)
        else            rowstart[N_NODES] = N_EDGES;
    }
}

// ---------------- csr fill body (predicated; packs (src, w*dinv[dst])) ----------------
__device__ inline void csr_pass(int blk, const int* __restrict__ src,
                                const int* __restrict__ dst,
                                const float* __restrict__ w,
                                const float* __restrict__ dinv,
                                const int* __restrict__ rowstart,
                                const unsigned int* __restrict__ slot,
                                u64* __restrict__ epack, bool isA) {
    int base = blk * 256 + threadIdx.x;
    if (base * 4 >= N_EDGES) return;
    int4   s4 = ((const int4*)src)[base];
    int4   d4 = ((const int4*)dst)[base];
    float4 w4 = ((const float4*)w)[base];
    uint4  r4 = ((const uint4*)slot)[base];
#define CPROC(SV, DV, WV, RV)                                                     \
    if (((DV) < NSPLIT) == isA) {                                                 \
        float pn = (WV) * dinv[DV];                                               \
        epack[rowstart[DV] + (int)(RV)] =                                         \
            (u64)(unsigned int)(SV) | ((u64)__float_as_uint(pn) << 32);           \
    }
    CPROC(s4.x, d4.x, w4.x, r4.x)
    CPROC(s4.y, d4.y, w4.y, r4.y)
    CPROC(s4.z, d4.z, w4.z, r4.z)
    CPROC(s4.w, d4.w, w4.w, r4.w)
#undef CPROC
}

// ---------------- gather body: 16 lanes/node over [nbase, nbase+25000) ----------------
__device__ inline void gather_body(int gblk, int nbase,
                                   const unsigned short* __restrict__ hb,
                                   const int* __restrict__ rowstart,
                                   const u64* __restrict__ epack,
                                   const float* __restrict__ dinv,
                                   const float* __restrict__ b,
                                   unsigned short* __restrict__ tmp) {
    const int t = threadIdx.x;
    const int n = nbase + gblk * 16 + (t >> 4);
    if (n >= nbase + NSPLIT || n >= N_NODES) return;
    const int c8 = (t & 15) * 8;
    const int s0 = rowstart[n];
    const int e0 = rowstart[n + 1];
    const float di = dinv[n];
    const float sl = di * di;
    float acc[8];
    {
        u16x8 hv = *(const u16x8*)(hb + (size_t)n * HIDDEN + c8);
#pragma unroll
        for (int j = 0; j < 8; ++j) acc[j] = sl * b2f(hv[j]);
    }
    int p = s0;
    for (; p + 4 <= e0; p += 4) {
        u64 e1 = epack[p];
        u64 e2 = epack[p + 1];
        u64 e3 = epack[p + 2];
        u64 e4 = epack[p + 3];
        int x1 = (int)(unsigned int)e1;
        int x2 = (int)(unsigned int)e2;
        int x3 = (int)(unsigned int)e3;
        int x4 = (int)(unsigned int)e4;
        float n1 = __uint_as_float((unsigned int)(e1 >> 32)) * dinv[x1];
        float n2 = __uint_as_float((unsigned int)(e2 >> 32)) * dinv[x2];
        float n3 = __uint_as_float((unsigned int)(e3 >> 32)) * dinv[x3];
        float n4 = __uint_as_float((unsigned int)(e4 >> 32)) * dinv[x4];
        u16x8 v1 = *(const u16x8*)(hb + (size_t)x1 * HIDDEN + c8);
        u16x8 v2 = *(const u16x8*)(hb + (size_t)x2 * HIDDEN + c8);
        u16x8 v3 = *(const u16x8*)(hb + (size_t)x3 * HIDDEN + c8);
        u16x8 v4 = *(const u16x8*)(hb + (size_t)x4 * HIDDEN + c8);
#pragma unroll
        for (int j = 0; j < 8; ++j) acc[j] = fmaf(n1, b2f(v1[j]), acc[j]);
#pragma unroll
        for (int j = 0; j < 8; ++j) acc[j] = fmaf(n2, b2f(v2[j]), acc[j]);
#pragma unroll
        for (int j = 0; j < 8; ++j) acc[j] = fmaf(n3, b2f(v3[j]), acc[j]);
#pragma unroll
        for (int j = 0; j < 8; ++j) acc[j] = fmaf(n4, b2f(v4[j]), acc[j]);
    }
    for (; p < e0; ++p) {
        u64 e1 = epack[p];
        int x1 = (int)(unsigned int)e1;
        float n1 = __uint_as_float((unsigned int)(e1 >> 32)) * dinv[x1];
        u16x8 v1 = *(const u16x8*)(hb + (size_t)x1 * HIDDEN + c8);
#pragma unroll
        for (int j = 0; j < 8; ++j) acc[j] = fmaf(n1, b2f(v1[j]), acc[j]);
    }
    float4 b0 = *(const float4*)(b + c8);
    float4 b1 = *(const float4*)(b + c8 + 4);
    u16x8 o;
    o[0] = f2b(acc[0] + b0.x); o[1] = f2b(acc[1] + b0.y);
    o[2] = f2b(acc[2] + b0.z); o[3] = f2b(acc[3] + b0.w);
    o[4] = f2b(acc[4] + b1.x); o[5] = f2b(acc[5] + b1.y);
    o[6] = f2b(acc[6] + b1.z); o[7] = f2b(acc[7] + b1.w);
    *(u16x8*)(tmp + (size_t)n * HIDDEN + c8) = o;
}

// ---------------- stats+apply body (predicated by graph half) ----------------
__device__ inline void stats_body(int sblk,
                                  const unsigned short* __restrict__ tmp,
                                  const int* __restrict__ gstart,
                                  const float* __restrict__ ms,
                                  const float* __restrict__ gw,
                                  const float* __restrict__ gb,
                                  float* __restrict__ out, bool phaseA) {
    const int g = sblk >> 2;
    const int q = sblk & 3;
    const int l = threadIdx.x & 31;
    const int c = q * 32 + l;
    const int r = threadIdx.x >> 5;
    const int s = gstart[g];
    const int e = gstart[g + 1];
    if ((e <= NSPLIT) != phaseA) return;
    float sum = 0.f, sq = 0.f;
    for (int n = s + r; n < e; n += 8) {
        float v = b2f(tmp[(size_t)n * HIDDEN + c]);
        sum += v;
        sq = fmaf(v, v, sq);
    }
    __shared__ float ssum[8][32], ssq[8][32];
    __shared__ float sA[32], sS[32];
    ssum[r][l] = sum;
    ssq[r][l]  = sq;
    __syncthreads();
    if (r == 0) {
#pragma unroll
        for (int i = 1; i < 8; ++i) { sum += ssum[i][l]; sq += ssq[i][l]; }
        float cnt  = (float)max(e - s, 1);
        float mean = sum / cnt;
        float m2   = sq / cnt;
        float msv  = ms[c];
        float var  = fmaxf(m2 - mean * mean * msv * (2.f - msv), 0.f);
        float a    = gw[c] * rsqrtf(var + EPS_GN);
        sA[l] = a;
        sS[l] = gb[c] - a * msv * mean;
    }
    __syncthreads();
    float a  = sA[l];
    float sh = sS[l];
    for (int n = s + r; n < e; n += 8) {
        float v = b2f(tmp[(size_t)n * HIDDEN + c]);
        out[(size_t)n * HIDDEN + c] = fmaxf(fmaf(a, v, sh), 0.f);
    }
}

// ================= dispatches =================

// D1: gemm (blocks < NGEMM_BLK) + histA
__global__ __launch_bounds__(256) void d1_gemm_histA(const float* __restrict__ x,
                                                     const unsigned short* __restrict__ wb,
                                                     unsigned short* __restrict__ hb,
                                                     const int* __restrict__ dst,
                                                     const float* __restrict__ w,
                                                     unsigned int* __restrict__ cnt32,
                                                     unsigned int* __restrict__ slot) {
    if (blockIdx.x >= NGEMM_BLK) {
        hist_pass(blockIdx.x - NGEMM_BLK, dst, w, cnt32, slot, true);
        return;
    }
    const int wave = threadIdx.x >> 6;
    const int lane = threadIdx.x & 63;
    const int row0 = blockIdx.x * 64 + wave * 16;
    const int r  = lane & 15;
    const int ko = (lane >> 4) * 8;
    f32x4 acc[8];
#pragma unroll
    for (int t = 0; t < 8; ++t) { acc[t][0] = 0.f; acc[t][1] = 0.f; acc[t][2] = 0.f; acc[t][3] = 0.f; }
    int arow = row0 + r;
    if (arow >= N_NODES) arow = N_NODES - 1;
    const size_t abase = (size_t)arow * HIDDEN + ko;
#pragma unroll
    for (int kt = 0; kt < HIDDEN; kt += 32) {
        float4 a0 = *(const float4*)(x + abase + kt);
        float4 a1 = *(const float4*)(x + abase + kt + 4);
        bf16x8 a;
        a[0] = (__bf16)a0.x; a[1] = (__bf16)a0.y; a[2] = (__bf16)a0.z; a[3] = (__bf16)a0.w;
        a[4] = (__bf16)a1.x; a[5] = (__bf16)a1.y; a[6] = (__bf16)a1.z; a[7] = (__bf16)a1.w;
#pragma unroll
        for (int t = 0; t < 8; ++t) {
            bf16x8 b = *(const bf16x8*)(wb + (size_t)(t * 16 + r) * HIDDEN + kt + ko);
            acc[t] = __builtin_amdgcn_mfma_f32_16x16x32_bf16(a, b, acc[t], 0, 0, 0);
        }
    }
    const int orow = row0 + (lane >> 4) * 4;
#pragma unroll
    for (int t = 0; t < 8; ++t) {
#pragma unroll
        for (int j = 0; j < 4; ++j) {
            int rr = orow + j;
            if (rr < N_NODES) hb[(size_t)rr * HIDDEN + t * 16 + r] = f2b(acc[t][j]);
        }
    }
}

// D2: histB (blocks < NHIST_BLK) + scanA
__global__ __launch_bounds__(256) void d2_histB_scanA(const int* __restrict__ dst,
                                                      const float* __restrict__ w,
                                                      unsigned int* __restrict__ cnt32,
                                                      unsigned int* __restrict__ slot,
                                                      unsigned int* __restrict__ bsumA,
                                                      unsigned int* __restrict__ done,
                                                      float* __restrict__ dinv,
                                                      const int* __restrict__ batch,
                                                      int* __restrict__ gstart,
                                                      int* __restrict__ rowstart) {
    if (blockIdx.x < NHIST_BLK) {
        hist_pass(blockIdx.x, dst, w, cnt32, slot, false);
        return;
    }
    scan_half(blockIdx.x - NHIST_BLK, 0, cnt32, bsumA, done, dinv, batch, gstart, rowstart);
}

// D3: csrA (blocks < NCSR_BLK) + scanB
__global__ __launch_bounds__(256) void d3_csrA_scanB(const int* __restrict__ src,
                                                     const int* __restrict__ dst,
                                                     const float* __restrict__ w,
                                                     const float* __restrict__ dinv,
                                                     const int* __restrict__ rowstart,
                                                     const unsigned int* __restrict__ slot,
                                                     u64* __restrict__ epack,
                                                     const unsigned int* __restrict__ cnt32,
                                                     unsigned int* __restrict__ bsumB,
                                                     unsigned int* __restrict__ done,
                                                     const int* __restrict__ batch,
                                                     int* __restrict__ gstart,
                                                     float* __restrict__ dinv_w,
                                                     int* __restrict__ rowstart_w) {
    if (blockIdx.x < NCSR_BLK) {
        csr_pass(blockIdx.x, src, dst, w, dinv, rowstart, slot, epack, true);
        return;
    }
    scan_half(blockIdx.x - NCSR_BLK, NSPLIT, cnt32, bsumB, done, dinv_w, batch, gstart, rowstart_w);
}

// D4: gatherA (blocks < NGATH_BLK) + csrB
__global__ __launch_bounds__(256) void d4_gatherA_csrB(const unsigned short* __restrict__ hb,
                                                       const int* __restrict__ rowstart,
                                                       const u64* __restrict__ epack,
                                                       const float* __restrict__ dinv,
                                                       const float* __restrict__ b,
                                                       unsigned short* __restrict__ tmp,
                                                       const int* __restrict__ src,
                                                       const int* __restrict__ dst,
                                                       const float* __restrict__ w,
                                                       const unsigned int* __restrict__ slot,
                                                       u64* __restrict__ epack_w) {
    if (blockIdx.x < NGATH_BLK) {
        gather_body(blockIdx.x, 0, hb, rowstart, epack, dinv, b, tmp);
        return;
    }
    csr_pass(blockIdx.x - NGATH_BLK, src, dst, w, dinv, rowstart, slot, epack_w, false);
}

// D5: gatherB (blocks < NGATH_BLK) + statsA
__global__ __launch_bounds__(256) void d5_gatherB_statsA(const unsigned short* __restrict__ hb,
                                                         const int* __restrict__ rowstart,
                                                         const u64* __restrict__ epack,
                                                         const float* __restrict__ dinv,
                                                         const float* __restrict__ b,
                                                         unsigned short* __restrict__ tmp,
                                                         const int* __restrict__ gstart,
                                                         const float* __restrict__ ms,
                                                         const float* __restrict__ gw,
                                                         const float* __restrict__ gb,
                                                         float* __restrict__ out) {
    if (blockIdx.x < NGATH_BLK) {
        gather_body(blockIdx.x, NSPLIT, hb, rowstart, epack, dinv, b, tmp);
        return;
    }
    stats_body(blockIdx.x - NGATH_BLK, tmp, gstart, ms, gw, gb, out, true);
}

// D6: statsB
__global__ __launch_bounds__(256) void d6_statsB(const unsigned short* __restrict__ tmp,
                                                 const int* __restrict__ gstart,
                                                 const float* __restrict__ ms,
                                                 const float* __restrict__ gw,
                                                 const float* __restrict__ gb,
                                                 float* __restrict__ out) {
    stats_body(blockIdx.x, tmp, gstart, ms, gw, gb, out, false);
}

extern "C" void kernel_launch(void* const* d_in, const int* in_sizes, int n_in,
                              void* d_out, int out_size, void* d_ws, size_t ws_size,
                              hipStream_t stream) {
    const float* node  = (const float*)d_in[0];
    const int*   ei    = (const int*)d_in[1];
    const float* eattr = (const float*)d_in[2];
    const int*   batch = (const int*)d_in[3];
    const float* W     = (const float*)d_in[4];
    const float* b     = (const float*)d_in[5];
    const float* gnw   = (const float*)d_in[6];
    const float* gnb   = (const float*)d_in[7];
    const float* gnms  = (const float*)d_in[8];
    float* out = (float*)d_out;
    float* ws  = (float*)d_ws;

    const int* src = ei;
    const int* dst = ei + N_EDGES;

    unsigned short* hb   = (unsigned short*)(ws + HB_OFF);
    unsigned int*  cnt32 = (unsigned int*)(ws + CNT_OFF);
    unsigned int*  done  = (unsigned int*)(ws + DONE_OFF);
    unsigned int*  bsumA = (unsigned int*)(ws + BSUMA_OFF);
    unsigned int*  bsumB = (unsigned int*)(ws + BSUMB_OFF);
    float* dinv          = ws + DINV_OFF;
    unsigned short* wb   = (unsigned short*)(ws + WB_OFF);
    int*   gstart        = (int*)(ws + GSTART_OFF);
    int*   rowstart      = (int*)(ws + ROWS_OFF);
    u64*   epack         = (u64*)(ws + EPACK_OFF);
    unsigned int* slot   = (unsigned int*)(ws + SLOT_OFF);
    unsigned short* tmp  = (unsigned short*)(ws + TMP_OFF);

    prep<<<98, 256, 0, stream>>>(W, wb, (uint4*)cnt32);
    d1_gemm_histA<<<NGEMM_BLK + NHIST_BLK, 256, 0, stream>>>(node, wb, hb, dst, eattr, cnt32, slot);
    d2_histB_scanA<<<NHIST_BLK + NB_HALF, 256, 0, stream>>>(dst, eattr, cnt32, slot, bsumA, done,
                                                            dinv, batch, gstart, rowstart);
    d3_csrA_scanB<<<NCSR_BLK + NB_HALF, 256, 0, stream>>>(src, dst, eattr, dinv, rowstart, slot, epack,
                                                          cnt32, bsumB, done + 1, batch, gstart,
                                                          dinv, rowstart);
    d4_gatherA_csrB<<<NGATH_BLK + NCSR_BLK, 256, 0, stream>>>(hb, rowstart, epack, dinv, b, tmp,
                                                              src, dst, eattr, slot, epack);
    d5_gatherB_statsA<<<NGATH_BLK + 512, 256, 0, stream>>>(hb, rowstart, epack, dinv, b, tmp,
                                                           gstart, gnms, gnw, gnb, out);
    d6_statsB<<<512, 256, 0, stream>>>(tmp, gstart, gnms, gnw, gnb, out);

    (void)in_sizes; (void)n_in; (void)out_size; (void)ws_size;
}

// Round 15
// 127.905 us; speedup vs baseline: 1.2754x; 1.2754x over previous
//
#include <hip/hip_runtime.h>

#define N_NODES    50000
#define N_EDGES    625000
#define HIDDEN     128
#define NUM_GRAPHS 128
#define EPS_GN     1e-5f
#define FIXSCALE   1048576.0f   // 2^20 fixed point for degree accumulation
#define NGEMM_BLK  782          // (N_NODES + 63) / 64
#define NHIST_BLK  306          // ceil(N_EDGES/8/256)
#define NB_SCAN    196          // ceil(N_NODES/256)

typedef __bf16 bf16x8 __attribute__((ext_vector_type(8)));
typedef float  f32x4  __attribute__((ext_vector_type(4)));
typedef unsigned short u16x8 __attribute__((ext_vector_type(8)));
typedef unsigned long long u64;

__device__ inline unsigned short f2b(float f) {
    __bf16 b = (__bf16)f;
    return __builtin_bit_cast(unsigned short, b);
}
__device__ inline float b2f(unsigned short u) {
    unsigned int x = ((unsigned int)u) << 16;
    return __builtin_bit_cast(float, x);
}

// ---- workspace layout (4B units) ----
#define HB_OFF     0          // ushort[6,400,000] bf16(h)   -> 3,200,000 units
#define CNT64_OFF  3200000    // u64[50,000]                 -> 100,000 units
#define DINV_OFF   3300000    // float[50,000]
#define WB_OFF     3352000    // ushort[16,384]
#define GSTART_OFF 3362000    // int[129]
#define ROWS_OFF   3363000    // int[50,001]
#define BSUM_OFF   3414000    // int[256]
#define EPACK_OFF  3414100    // u64[625,000] (even offset)  -> 1,250,000 units
#define SLOT_OFF   4664100    // u32[625,000]
#define TMP_OFF    4664100    // ushort[6,400,000] overlays SLOT (dead after csr_fill); end 7,864,100 units = 31.5 MB

// ---------------- prep: zero cnt64 + convert W -> bf16 ----------------
__global__ void prep(const float* __restrict__ W, unsigned short* __restrict__ wb,
                     uint4* __restrict__ cntz) {
    int i = blockIdx.x * 256 + threadIdx.x;
    if (i < 100000 / 4) cntz[i] = make_uint4(0u, 0u, 0u, 0u);
    if (i < HIDDEN * HIDDEN) wb[i] = f2b(W[i]);
}

// ---------------- fused: GEMM tiles + edge histogram (8 edges/thread) ----------------
__global__ __launch_bounds__(256) void gemm_hist(const float* __restrict__ x,
                                                 const unsigned short* __restrict__ wb,
                                                 unsigned short* __restrict__ hb,
                                                 const int* __restrict__ dst,
                                                 const float* __restrict__ w,
                                                 u64* __restrict__ cnt64,
                                                 unsigned int* __restrict__ slot) {
    if (blockIdx.x >= NGEMM_BLK) {
        int base = (blockIdx.x - NGEMM_BLK) * 256 + threadIdx.x;   // 8-edge group id
        if (base * 8 >= N_EDGES) return;
        int4   dA = ((const int4*)dst)[base * 2];
        int4   dB = ((const int4*)dst)[base * 2 + 1];
        float4 wA = ((const float4*)w)[base * 2];
        float4 wB = ((const float4*)w)[base * 2 + 1];
        uint4 sA, sB;
        {
            unsigned int fx = (unsigned int)(wA.x * FIXSCALE + 0.5f);
            sA.x = (unsigned int)(atomicAdd(&cnt64[dA.x], (1ULL << 32) | (u64)fx) >> 32);
            fx = (unsigned int)(wA.y * FIXSCALE + 0.5f);
            sA.y = (unsigned int)(atomicAdd(&cnt64[dA.y], (1ULL << 32) | (u64)fx) >> 32);
            fx = (unsigned int)(wA.z * FIXSCALE + 0.5f);
            sA.z = (unsigned int)(atomicAdd(&cnt64[dA.z], (1ULL << 32) | (u64)fx) >> 32);
            fx = (unsigned int)(wA.w * FIXSCALE + 0.5f);
            sA.w = (unsigned int)(atomicAdd(&cnt64[dA.w], (1ULL << 32) | (u64)fx) >> 32);
            fx = (unsigned int)(wB.x * FIXSCALE + 0.5f);
            sB.x = (unsigned int)(atomicAdd(&cnt64[dB.x], (1ULL << 32) | (u64)fx) >> 32);
            fx = (unsigned int)(wB.y * FIXSCALE + 0.5f);
            sB.y = (unsigned int)(atomicAdd(&cnt64[dB.y], (1ULL << 32) | (u64)fx) >> 32);
            fx = (unsigned int)(wB.z * FIXSCALE + 0.5f);
            sB.z = (unsigned int)(atomicAdd(&cnt64[dB.z], (1ULL << 32) | (u64)fx) >> 32);
            fx = (unsigned int)(wB.w * FIXSCALE + 0.5f);
            sB.w = (unsigned int)(atomicAdd(&cnt64[dB.w], (1ULL << 32) | (u64)fx) >> 32);
        }
        ((uint4*)slot)[base * 2]     = sA;
        ((uint4*)slot)[base * 2 + 1] = sB;
        return;
    }
    // ---- GEMM part: h = x @ W.T ----
    const int wave = threadIdx.x >> 6;
    const int lane = threadIdx.x & 63;
    const int row0 = blockIdx.x * 64 + wave * 16;
    const int r  = lane & 15;
    const int ko = (lane >> 4) * 8;
    f32x4 acc[8];
#pragma unroll
    for (int t = 0; t < 8; ++t) { acc[t][0] = 0.f; acc[t][1] = 0.f; acc[t][2] = 0.f; acc[t][3] = 0.f; }
    int arow = row0 + r;
    if (arow >= N_NODES) arow = N_NODES - 1;
    const size_t abase = (size_t)arow * HIDDEN + ko;
#pragma unroll
    for (int kt = 0; kt < HIDDEN; kt += 32) {
        float4 a0 = *(const float4*)(x + abase + kt);
        float4 a1 = *(const float4*)(x + abase + kt + 4);
        bf16x8 a;
        a[0] = (__bf16)a0.x; a[1] = (__bf16)a0.y; a[2] = (__bf16)a0.z; a[3] = (__bf16)a0.w;
        a[4] = (__bf16)a1.x; a[5] = (__bf16)a1.y; a[6] = (__bf16)a1.z; a[7] = (__bf16)a1.w;
#pragma unroll
        for (int t = 0; t < 8; ++t) {
            bf16x8 b = *(const bf16x8*)(wb + (size_t)(t * 16 + r) * HIDDEN + kt + ko);
            acc[t] = __builtin_amdgcn_mfma_f32_16x16x32_bf16(a, b, acc[t], 0, 0, 0);
        }
    }
    const int orow = row0 + (lane >> 4) * 4;
#pragma unroll
    for (int t = 0; t < 8; ++t) {
#pragma unroll
        for (int j = 0; j < 4; ++j) {
            int rr = orow + j;
            if (rr < N_NODES) hb[(size_t)rr * HIDDEN + t * 16 + r] = f2b(acc[t][j]);
        }
    }
}

// ---------------- scan partials + dinv + graph bounds (fused) ----------------
__global__ void scan_partial(const u64* __restrict__ cnt64, int* __restrict__ bsum,
                             float* __restrict__ dinv,
                             const int* __restrict__ batch, int* __restrict__ gstart) {
    __shared__ int red[256];
    int i = blockIdx.x * 256 + threadIdx.x;
    int c = 0;
    if (i < N_NODES) {
        u64 v = cnt64[i];
        c = (int)(v >> 32);
        dinv[i] = rsqrtf(1.0f + (float)(unsigned int)v * (1.0f / FIXSCALE));
        int b0 = batch[i];
        int prev = (i == 0) ? -1 : batch[i - 1];
        for (int g = prev + 1; g <= b0; ++g) gstart[g] = i;
        if (i == N_NODES - 1) {
            for (int g = b0 + 1; g <= NUM_GRAPHS; ++g) gstart[g] = N_NODES;
        }
    }
    red[threadIdx.x] = c;
    __syncthreads();
    for (int off = 128; off > 0; off >>= 1) {
        if (threadIdx.x < off) red[threadIdx.x] += red[threadIdx.x + off];
        __syncthreads();
    }
    if (threadIdx.x == 0) bsum[blockIdx.x] = red[0];
}

// ---------------- scan_emit with inlined block-offset scan ----------------
__global__ void scan_emit(const u64* __restrict__ cnt64, const int* __restrict__ bsum,
                          int* __restrict__ rowstart) {
    __shared__ int sb[256];
    __shared__ int s[256];
    int t = threadIdx.x;
    sb[t] = (t < NB_SCAN) ? bsum[t] : 0;
    __syncthreads();
    for (int off = 1; off < 256; off <<= 1) {
        int v = (t >= off) ? sb[t - off] : 0;
        __syncthreads();
        sb[t] += v;
        __syncthreads();
    }
    int boff = (blockIdx.x == 0) ? 0 : sb[blockIdx.x - 1];
    int i = blockIdx.x * 256 + t;
    int v0 = (i < N_NODES) ? (int)(cnt64[i] >> 32) : 0;
    s[t] = v0;
    __syncthreads();
    for (int off = 1; off < 256; off <<= 1) {
        int v = (t >= off) ? s[t - off] : 0;
        __syncthreads();
        s[t] += v;
        __syncthreads();
    }
    if (i < N_NODES) rowstart[i] = boff + s[t] - v0;
    if (i == N_NODES) rowstart[N_NODES] = N_EDGES;
}

// ---------------- fill CSR: atomic-free, 8 edges/thread ----------------
__global__ void csr_fill(const int* __restrict__ src, const int* __restrict__ dst,
                         const float* __restrict__ w, const float* __restrict__ dinv,
                         const int* __restrict__ rowstart, const unsigned int* __restrict__ slot,
                         u64* __restrict__ epack) {
    int base = blockIdx.x * blockDim.x + threadIdx.x;
    if (base * 8 >= N_EDGES) return;
    int4   sA = ((const int4*)src)[base * 2];
    int4   sB = ((const int4*)src)[base * 2 + 1];
    int4   dA = ((const int4*)dst)[base * 2];
    int4   dB = ((const int4*)dst)[base * 2 + 1];
    float4 wA = ((const float4*)w)[base * 2];
    float4 wB = ((const float4*)w)[base * 2 + 1];
    uint4  rA = ((const uint4*)slot)[base * 2];
    uint4  rB = ((const uint4*)slot)[base * 2 + 1];
#define CPROC(SV, DV, WV, RV)                                                  \
    {                                                                          \
        float nm = dinv[SV] * (WV) * dinv[DV];                                 \
        epack[rowstart[DV] + (int)(RV)] =                                      \
            (u64)(unsigned int)(SV) | ((u64)__float_as_uint(nm) << 32);        \
    }
    CPROC(sA.x, dA.x, wA.x, rA.x)
    CPROC(sA.y, dA.y, wA.y, rA.y)
    CPROC(sA.z, dA.z, wA.z, rA.z)
    CPROC(sA.w, dA.w, wA.w, rA.w)
    CPROC(sB.x, dB.x, wB.x, rB.x)
    CPROC(sB.y, dB.y, wB.y, rB.y)
    CPROC(sB.z, dB.z, wB.z, rB.z)
    CPROC(sB.w, dB.w, wB.w, rB.w)
#undef CPROC
}

// ---------------- gather: 16 lanes/node, 4-edge unroll, writes bf16 tmp ----------------
__global__ __launch_bounds__(256) void gather_fused(const unsigned short* __restrict__ hb,
                                                    const int* __restrict__ rowstart,
                                                    const u64* __restrict__ epack,
                                                    const float* __restrict__ dinv,
                                                    const float* __restrict__ b,
                                                    unsigned short* __restrict__ tmp) {
    const int t = threadIdx.x;
    const int n = blockIdx.x * 16 + (t >> 4);
    if (n >= N_NODES) return;
    const int c8 = (t & 15) * 8;
    const int s0 = rowstart[n];
    const int e0 = rowstart[n + 1];
    const float di = dinv[n];
    const float sl = di * di;
    float acc[8];
    {
        u16x8 hv = *(const u16x8*)(hb + (size_t)n * HIDDEN + c8);
#pragma unroll
        for (int j = 0; j < 8; ++j) acc[j] = sl * b2f(hv[j]);
    }
    int p = s0;
    for (; p + 4 <= e0; p += 4) {
        u64 e1 = epack[p];
        u64 e2 = epack[p + 1];
        u64 e3 = epack[p + 2];
        u64 e4 = epack[p + 3];
        int   x1 = (int)(unsigned int)e1;
        int   x2 = (int)(unsigned int)e2;
        int   x3 = (int)(unsigned int)e3;
        int   x4 = (int)(unsigned int)e4;
        float n1 = __uint_as_float((unsigned int)(e1 >> 32));
        float n2 = __uint_as_float((unsigned int)(e2 >> 32));
        float n3 = __uint_as_float((unsigned int)(e3 >> 32));
        float n4 = __uint_as_float((unsigned int)(e4 >> 32));
        u16x8 v1 = *(const u16x8*)(hb + (size_t)x1 * HIDDEN + c8);
        u16x8 v2 = *(const u16x8*)(hb + (size_t)x2 * HIDDEN + c8);
        u16x8 v3 = *(const u16x8*)(hb + (size_t)x3 * HIDDEN + c8);
        u16x8 v4 = *(const u16x8*)(hb + (size_t)x4 * HIDDEN + c8);
#pragma unroll
        for (int j = 0; j < 8; ++j) acc[j] = fmaf(n1, b2f(v1[j]), acc[j]);
#pragma unroll
        for (int j = 0; j < 8; ++j) acc[j] = fmaf(n2, b2f(v2[j]), acc[j]);
#pragma unroll
        for (int j = 0; j < 8; ++j) acc[j] = fmaf(n3, b2f(v3[j]), acc[j]);
#pragma unroll
        for (int j = 0; j < 8; ++j) acc[j] = fmaf(n4, b2f(v4[j]), acc[j]);
    }
    for (; p < e0; ++p) {
        u64 e1 = epack[p];
        int   x1 = (int)(unsigned int)e1;
        float n1 = __uint_as_float((unsigned int)(e1 >> 32));
        u16x8 v1 = *(const u16x8*)(hb + (size_t)x1 * HIDDEN + c8);
#pragma unroll
        for (int j = 0; j < 8; ++j) acc[j] = fmaf(n1, b2f(v1[j]), acc[j]);
    }
    float4 b0 = *(const float4*)(b + c8);
    float4 b1 = *(const float4*)(b + c8 + 4);
    u16x8 o;
    o[0] = f2b(acc[0] + b0.x); o[1] = f2b(acc[1] + b0.y);
    o[2] = f2b(acc[2] + b0.z); o[3] = f2b(acc[3] + b0.w);
    o[4] = f2b(acc[4] + b1.x); o[5] = f2b(acc[5] + b1.y);
    o[6] = f2b(acc[6] + b1.z); o[7] = f2b(acc[7] + b1.w);
    *(u16x8*)(tmp + (size_t)n * HIDDEN + c8) = o;
}

// ---------------- fused per-graph stats + normalize + relu ----------------
__global__ __launch_bounds__(256) void stats_apply(const unsigned short* __restrict__ tmp,
                                                   const int* __restrict__ gstart,
                                                   const float* __restrict__ ms,
                                                   const float* __restrict__ gw,
                                                   const float* __restrict__ gb,
                                                   float* __restrict__ out) {
    const int g = blockIdx.x >> 2;
    const int q = blockIdx.x & 3;
    const int l = threadIdx.x & 31;
    const int c = q * 32 + l;
    const int r = threadIdx.x >> 5;
    const int s = gstart[g];
    const int e = gstart[g + 1];
    float sum = 0.f, sq = 0.f;
    for (int n = s + r; n < e; n += 8) {
        float v = b2f(tmp[(size_t)n * HIDDEN + c]);
        sum += v;
        sq = fmaf(v, v, sq);
    }
    __shared__ float ssum[8][32], ssq[8][32];
    __shared__ float sA[32], sS[32];
    ssum[r][l] = sum;
    ssq[r][l]  = sq;
    __syncthreads();
    if (r == 0) {
#pragma unroll
        for (int i = 1; i < 8; ++i) { sum += ssum[i][l]; sq += ssq[i][l]; }
        float cnt  = (float)max(e - s, 1);
        float mean = sum / cnt;
        float m2   = sq / cnt;
        float msv  = ms[c];
        float var  = fmaxf(m2 - mean * mean * msv * (2.f - msv), 0.f);
        float a    = gw[c] * rsqrtf(var + EPS_GN);
        sA[l] = a;
        sS[l] = gb[c] - a * msv * mean;
    }
    __syncthreads();
    float a  = sA[l];
    float sh = sS[l];
    for (int n = s + r; n < e; n += 8) {
        float v = b2f(tmp[(size_t)n * HIDDEN + c]);
        out[(size_t)n * HIDDEN + c] = fmaxf(fmaf(a, v, sh), 0.f);
    }
}

extern "C" void kernel_launch(void* const* d_in, const int* in_sizes, int n_in,
                              void* d_out, int out_size, void* d_ws, size_t ws_size,
                              hipStream_t stream) {
    const float* node  = (const float*)d_in[0];
    const int*   ei    = (const int*)d_in[1];
    const float* eattr = (const float*)d_in[2];
    const int*   batch = (const int*)d_in[3];
    const float* W     = (const float*)d_in[4];
    const float* b     = (const float*)d_in[5];
    const float* gnw   = (const float*)d_in[6];
    const float* gnb   = (const float*)d_in[7];
    const float* gnms  = (const float*)d_in[8];
    float* out = (float*)d_out;
    float* ws  = (float*)d_ws;

    const int* src = ei;
    const int* dst = ei + N_EDGES;

    unsigned short* hb = (unsigned short*)(ws + HB_OFF);
    u64*   cnt64   = (u64*)(ws + CNT64_OFF);
    float* dinv    = ws + DINV_OFF;
    unsigned short* wb = (unsigned short*)(ws + WB_OFF);
    int*   gstart  = (int*)(ws + GSTART_OFF);
    int*   rowstart= (int*)(ws + ROWS_OFF);
    int*   bsum    = (int*)(ws + BSUM_OFF);
    u64*   epack   = (u64*)(ws + EPACK_OFF);
    unsigned int* slot = (unsigned int*)(ws + SLOT_OFF + 1250000);  // place slot after epack region? no — keep distinct
    // NOTE: slot must NOT overlap tmp while alive. slot lives at its own region:
    slot = (unsigned int*)(ws + 4664100);
    unsigned short* tmp = (unsigned short*)(ws + TMP_OFF);   // overlays slot (slot dead after csr_fill)

    prep<<<98, 256, 0, stream>>>(W, wb, (uint4*)cnt64);
    gemm_hist<<<NGEMM_BLK + NHIST_BLK, 256, 0, stream>>>(node, wb, hb, dst, eattr, cnt64, slot);
    scan_partial<<<NB_SCAN, 256, 0, stream>>>(cnt64, bsum, dinv, batch, gstart);
    scan_emit<<<NB_SCAN, 256, 0, stream>>>(cnt64, bsum, rowstart);
    csr_fill<<<NHIST_BLK, 256, 0, stream>>>(src, dst, eattr, dinv, rowstart, slot, epack);
    gather_fused<<<(N_NODES + 15) / 16, 256, 0, stream>>>(hb, rowstart, epack, dinv, b, tmp);
    stats_apply<<<NUM_GRAPHS * 4, 256, 0, stream>>>(tmp, gstart, gnms, gnw, gnb, out);

    (void)in_sizes; (void)n_in; (void)out_size; (void)ws_size;
}

// Round 16
// 113.267 us; speedup vs baseline: 1.4402x; 1.1292x over previous
//
#include <hip/hip_runtime.h>

#define N_NODES    50000
#define N_EDGES    625000
#define HIDDEN     128
#define NUM_GRAPHS 128
#define EPS_GN     1e-5f
#define FIXSCALE   1048576.0f   // 2^20 fixed point for degree accumulation
#define NGEMM_BLK  782          // (N_NODES + 63) / 64
#define NHIST_BLK  306          // ceil(N_EDGES/8/256)
#define NB_SCAN    196          // ceil(N_NODES/256)

typedef __bf16 bf16x8 __attribute__((ext_vector_type(8)));
typedef float  f32x4  __attribute__((ext_vector_type(4)));
typedef unsigned short u16x8 __attribute__((ext_vector_type(8)));
typedef unsigned short u16x4 __attribute__((ext_vector_type(4)));
typedef unsigned long long u64;

__device__ inline unsigned short f2b(float f) {
    __bf16 b = (__bf16)f;
    return __builtin_bit_cast(unsigned short, b);
}
__device__ inline float b2f(unsigned short u) {
    unsigned int x = ((unsigned int)u) << 16;
    return __builtin_bit_cast(float, x);
}

// ---- workspace layout (4B units) ----
#define HB_OFF     0          // ushort[6,400,000] bf16(h)   -> 3,200,000 units
#define CNT64_OFF  3200000    // u64[50,000]                 -> 100,000 units
#define DINV_OFF   3300000    // float[50,000]
#define WB_OFF     3352000    // ushort[16,384]
#define GSTART_OFF 3362000    // int[129]
#define ROWS_OFF   3363000    // int[50,001]
#define BSUM_OFF   3414000    // int[256]
#define EPACK_OFF  3414100    // u64[625,000] (8B-aligned)   -> 1,250,000 units
#define SLOT_OFF   4664100    // u32[625,000]
#define TMP_OFF    4664100    // ushort[6,400,000] overlays SLOT (dead after csr_fill); 16B-aligned

// ---------------- prep: zero cnt64 + convert W -> bf16 ----------------
__global__ void prep(const float* __restrict__ W, unsigned short* __restrict__ wb,
                     uint4* __restrict__ cntz) {
    int i = blockIdx.x * 256 + threadIdx.x;
    if (i < 100000 / 4) cntz[i] = make_uint4(0u, 0u, 0u, 0u);
    if (i < HIDDEN * HIDDEN) wb[i] = f2b(W[i]);
}

// ---------------- fused: GEMM tiles + edge histogram (8 edges/thread) ----------------
__global__ __launch_bounds__(256) void gemm_hist(const float* __restrict__ x,
                                                 const unsigned short* __restrict__ wb,
                                                 unsigned short* __restrict__ hb,
                                                 const int* __restrict__ dst,
                                                 const float* __restrict__ w,
                                                 u64* __restrict__ cnt64,
                                                 unsigned int* __restrict__ slot) {
    if (blockIdx.x >= NGEMM_BLK) {
        int base = (blockIdx.x - NGEMM_BLK) * 256 + threadIdx.x;   // 8-edge group id
        if (base * 8 >= N_EDGES) return;
        int4   dA = ((const int4*)dst)[base * 2];
        int4   dB = ((const int4*)dst)[base * 2 + 1];
        float4 wA = ((const float4*)w)[base * 2];
        float4 wB = ((const float4*)w)[base * 2 + 1];
        uint4 sA, sB;
        {
            unsigned int fx = (unsigned int)(wA.x * FIXSCALE + 0.5f);
            sA.x = (unsigned int)(atomicAdd(&cnt64[dA.x], (1ULL << 32) | (u64)fx) >> 32);
            fx = (unsigned int)(wA.y * FIXSCALE + 0.5f);
            sA.y = (unsigned int)(atomicAdd(&cnt64[dA.y], (1ULL << 32) | (u64)fx) >> 32);
            fx = (unsigned int)(wA.z * FIXSCALE + 0.5f);
            sA.z = (unsigned int)(atomicAdd(&cnt64[dA.z], (1ULL << 32) | (u64)fx) >> 32);
            fx = (unsigned int)(wA.w * FIXSCALE + 0.5f);
            sA.w = (unsigned int)(atomicAdd(&cnt64[dA.w], (1ULL << 32) | (u64)fx) >> 32);
            fx = (unsigned int)(wB.x * FIXSCALE + 0.5f);
            sB.x = (unsigned int)(atomicAdd(&cnt64[dB.x], (1ULL << 32) | (u64)fx) >> 32);
            fx = (unsigned int)(wB.y * FIXSCALE + 0.5f);
            sB.y = (unsigned int)(atomicAdd(&cnt64[dB.y], (1ULL << 32) | (u64)fx) >> 32);
            fx = (unsigned int)(wB.z * FIXSCALE + 0.5f);
            sB.z = (unsigned int)(atomicAdd(&cnt64[dB.z], (1ULL << 32) | (u64)fx) >> 32);
            fx = (unsigned int)(wB.w * FIXSCALE + 0.5f);
            sB.w = (unsigned int)(atomicAdd(&cnt64[dB.w], (1ULL << 32) | (u64)fx) >> 32);
        }
        ((uint4*)slot)[base * 2]     = sA;
        ((uint4*)slot)[base * 2 + 1] = sB;
        return;
    }
    // ---- GEMM part: h = x @ W.T ----
    const int wave = threadIdx.x >> 6;
    const int lane = threadIdx.x & 63;
    const int row0 = blockIdx.x * 64 + wave * 16;
    const int r  = lane & 15;
    const int ko = (lane >> 4) * 8;
    f32x4 acc[8];
#pragma unroll
    for (int t = 0; t < 8; ++t) { acc[t][0] = 0.f; acc[t][1] = 0.f; acc[t][2] = 0.f; acc[t][3] = 0.f; }
    int arow = row0 + r;
    if (arow >= N_NODES) arow = N_NODES - 1;
    const size_t abase = (size_t)arow * HIDDEN + ko;
#pragma unroll
    for (int kt = 0; kt < HIDDEN; kt += 32) {
        float4 a0 = *(const float4*)(x + abase + kt);
        float4 a1 = *(const float4*)(x + abase + kt + 4);
        bf16x8 a;
        a[0] = (__bf16)a0.x; a[1] = (__bf16)a0.y; a[2] = (__bf16)a0.z; a[3] = (__bf16)a0.w;
        a[4] = (__bf16)a1.x; a[5] = (__bf16)a1.y; a[6] = (__bf16)a1.z; a[7] = (__bf16)a1.w;
#pragma unroll
        for (int t = 0; t < 8; ++t) {
            bf16x8 b = *(const bf16x8*)(wb + (size_t)(t * 16 + r) * HIDDEN + kt + ko);
            acc[t] = __builtin_amdgcn_mfma_f32_16x16x32_bf16(a, b, acc[t], 0, 0, 0);
        }
    }
    const int orow = row0 + (lane >> 4) * 4;
#pragma unroll
    for (int t = 0; t < 8; ++t) {
#pragma unroll
        for (int j = 0; j < 4; ++j) {
            int rr = orow + j;
            if (rr < N_NODES) hb[(size_t)rr * HIDDEN + t * 16 + r] = f2b(acc[t][j]);
        }
    }
}

// ---------------- scan partials + dinv + graph bounds (fused) ----------------
__global__ void scan_partial(const u64* __restrict__ cnt64, int* __restrict__ bsum,
                             float* __restrict__ dinv,
                             const int* __restrict__ batch, int* __restrict__ gstart) {
    __shared__ int red[256];
    int i = blockIdx.x * 256 + threadIdx.x;
    int c = 0;
    if (i < N_NODES) {
        u64 v = cnt64[i];
        c = (int)(v >> 32);
        dinv[i] = rsqrtf(1.0f + (float)(unsigned int)v * (1.0f / FIXSCALE));
        int b0 = batch[i];
        int prev = (i == 0) ? -1 : batch[i - 1];
        for (int g = prev + 1; g <= b0; ++g) gstart[g] = i;
        if (i == N_NODES - 1) {
            for (int g = b0 + 1; g <= NUM_GRAPHS; ++g) gstart[g] = N_NODES;
        }
    }
    red[threadIdx.x] = c;
    __syncthreads();
    for (int off = 128; off > 0; off >>= 1) {
        if (threadIdx.x < off) red[threadIdx.x] += red[threadIdx.x + off];
        __syncthreads();
    }
    if (threadIdx.x == 0) bsum[blockIdx.x] = red[0];
}

// ---------------- scan_emit with inlined block-offset scan ----------------
__global__ void scan_emit(const u64* __restrict__ cnt64, const int* __restrict__ bsum,
                          int* __restrict__ rowstart) {
    __shared__ int sb[256];
    __shared__ int s[256];
    int t = threadIdx.x;
    sb[t] = (t < NB_SCAN) ? bsum[t] : 0;
    __syncthreads();
    for (int off = 1; off < 256; off <<= 1) {
        int v = (t >= off) ? sb[t - off] : 0;
        __syncthreads();
        sb[t] += v;
        __syncthreads();
    }
    int boff = (blockIdx.x == 0) ? 0 : sb[blockIdx.x - 1];
    int i = blockIdx.x * 256 + t;
    int v0 = (i < N_NODES) ? (int)(cnt64[i] >> 32) : 0;
    s[t] = v0;
    __syncthreads();
    for (int off = 1; off < 256; off <<= 1) {
        int v = (t >= off) ? s[t - off] : 0;
        __syncthreads();
        s[t] += v;
        __syncthreads();
    }
    if (i < N_NODES) rowstart[i] = boff + s[t] - v0;
    if (i == N_NODES) rowstart[N_NODES] = N_EDGES;
}

// ---------------- fill CSR: atomic-free, 4 edges/thread ----------------
__global__ void csr_fill(const int* __restrict__ src, const int* __restrict__ dst,
                         const float* __restrict__ w, const float* __restrict__ dinv,
                         const int* __restrict__ rowstart, const unsigned int* __restrict__ slot,
                         u64* __restrict__ epack) {
    int base = blockIdx.x * blockDim.x + threadIdx.x;
    if (base * 4 >= N_EDGES) return;
    int4   s4 = ((const int4*)src)[base];
    int4   d4 = ((const int4*)dst)[base];
    float4 w4 = ((const float4*)w)[base];
    uint4  r4 = ((const uint4*)slot)[base];
    float nm0 = dinv[s4.x] * w4.x * dinv[d4.x];
    float nm1 = dinv[s4.y] * w4.y * dinv[d4.y];
    float nm2 = dinv[s4.z] * w4.z * dinv[d4.z];
    float nm3 = dinv[s4.w] * w4.w * dinv[d4.w];
    epack[rowstart[d4.x] + (int)r4.x] = (u64)(unsigned int)s4.x | ((u64)__float_as_uint(nm0) << 32);
    epack[rowstart[d4.y] + (int)r4.y] = (u64)(unsigned int)s4.y | ((u64)__float_as_uint(nm1) << 32);
    epack[rowstart[d4.z] + (int)r4.z] = (u64)(unsigned int)s4.z | ((u64)__float_as_uint(nm2) << 32);
    epack[rowstart[d4.w] + (int)r4.w] = (u64)(unsigned int)s4.w | ((u64)__float_as_uint(nm3) << 32);
}

// ---------------- gather: 16 lanes/node, 4-edge unroll, writes bf16 tmp ----------------
__global__ __launch_bounds__(256) void gather_fused(const unsigned short* __restrict__ hb,
                                                    const int* __restrict__ rowstart,
                                                    const u64* __restrict__ epack,
                                                    const float* __restrict__ dinv,
                                                    const float* __restrict__ b,
                                                    unsigned short* __restrict__ tmp) {
    const int t = threadIdx.x;
    const int n = blockIdx.x * 16 + (t >> 4);
    if (n >= N_NODES) return;
    const int c8 = (t & 15) * 8;
    const int s0 = rowstart[n];
    const int e0 = rowstart[n + 1];
    const float di = dinv[n];
    const float sl = di * di;
    float acc[8];
    {
        u16x8 hv = *(const u16x8*)(hb + (size_t)n * HIDDEN + c8);
#pragma unroll
        for (int j = 0; j < 8; ++j) acc[j] = sl * b2f(hv[j]);
    }
    int p = s0;
    for (; p + 4 <= e0; p += 4) {
        u64 e1 = epack[p];
        u64 e2 = epack[p + 1];
        u64 e3 = epack[p + 2];
        u64 e4 = epack[p + 3];
        int   x1 = (int)(unsigned int)e1;
        int   x2 = (int)(unsigned int)e2;
        int   x3 = (int)(unsigned int)e3;
        int   x4 = (int)(unsigned int)e4;
        float n1 = __uint_as_float((unsigned int)(e1 >> 32));
        float n2 = __uint_as_float((unsigned int)(e2 >> 32));
        float n3 = __uint_as_float((unsigned int)(e3 >> 32));
        float n4 = __uint_as_float((unsigned int)(e4 >> 32));
        u16x8 v1 = *(const u16x8*)(hb + (size_t)x1 * HIDDEN + c8);
        u16x8 v2 = *(const u16x8*)(hb + (size_t)x2 * HIDDEN + c8);
        u16x8 v3 = *(const u16x8*)(hb + (size_t)x3 * HIDDEN + c8);
        u16x8 v4 = *(const u16x8*)(hb + (size_t)x4 * HIDDEN + c8);
#pragma unroll
        for (int j = 0; j < 8; ++j) acc[j] = fmaf(n1, b2f(v1[j]), acc[j]);
#pragma unroll
        for (int j = 0; j < 8; ++j) acc[j] = fmaf(n2, b2f(v2[j]), acc[j]);
#pragma unroll
        for (int j = 0; j < 8; ++j) acc[j] = fmaf(n3, b2f(v3[j]), acc[j]);
#pragma unroll
        for (int j = 0; j < 8; ++j) acc[j] = fmaf(n4, b2f(v4[j]), acc[j]);
    }
    for (; p < e0; ++p) {
        u64 e1 = epack[p];
        int   x1 = (int)(unsigned int)e1;
        float n1 = __uint_as_float((unsigned int)(e1 >> 32));
        u16x8 v1 = *(const u16x8*)(hb + (size_t)x1 * HIDDEN + c8);
#pragma unroll
        for (int j = 0; j < 8; ++j) acc[j] = fmaf(n1, b2f(v1[j]), acc[j]);
    }
    float4 b0 = *(const float4*)(b + c8);
    float4 b1 = *(const float4*)(b + c8 + 4);
    u16x8 o;
    o[0] = f2b(acc[0] + b0.x); o[1] = f2b(acc[1] + b0.y);
    o[2] = f2b(acc[2] + b0.z); o[3] = f2b(acc[3] + b0.w);
    o[4] = f2b(acc[4] + b1.x); o[5] = f2b(acc[5] + b1.y);
    o[6] = f2b(acc[6] + b1.z); o[7] = f2b(acc[7] + b1.w);
    *(u16x8*)(tmp + (size_t)n * HIDDEN + c8) = o;
}

// ---------------- fused per-graph stats + normalize + relu (vectorized u16x4/float4) ----------------
__global__ __launch_bounds__(256) void stats_apply(const unsigned short* __restrict__ tmp,
                                                   const int* __restrict__ gstart,
                                                   const float* __restrict__ ms,
                                                   const float* __restrict__ gw,
                                                   const float* __restrict__ gb,
                                                   float* __restrict__ out) {
    const int g = blockIdx.x >> 2;
    const int q = blockIdx.x & 3;
    const int l = threadIdx.x & 7;        // col group: 4 cols each
    const int r = threadIdx.x >> 3;       // 0..31 rows in flight
    const int c0 = q * 32 + l * 4;
    const int s = gstart[g];
    const int e = gstart[g + 1];
    float sum0 = 0.f, sum1 = 0.f, sum2 = 0.f, sum3 = 0.f;
    float sq0 = 0.f, sq1 = 0.f, sq2 = 0.f, sq3 = 0.f;
    for (int n = s + r; n < e; n += 32) {
        u16x4 v = *(const u16x4*)(tmp + (size_t)n * HIDDEN + c0);
        float x0 = b2f(v[0]), x1 = b2f(v[1]), x2 = b2f(v[2]), x3 = b2f(v[3]);
        sum0 += x0; sum1 += x1; sum2 += x2; sum3 += x3;
        sq0 = fmaf(x0, x0, sq0); sq1 = fmaf(x1, x1, sq1);
        sq2 = fmaf(x2, x2, sq2); sq3 = fmaf(x3, x3, sq3);
    }
    __shared__ float ssum[32][8][4];
    __shared__ float ssq[32][8][4];
    __shared__ float sA[32], sS[32];
    ssum[r][l][0] = sum0; ssum[r][l][1] = sum1; ssum[r][l][2] = sum2; ssum[r][l][3] = sum3;
    ssq[r][l][0]  = sq0;  ssq[r][l][1]  = sq1;  ssq[r][l][2]  = sq2;  ssq[r][l][3]  = sq3;
    __syncthreads();
    for (int off = 16; off > 0; off >>= 1) {
        if (r < off) {
#pragma unroll
            for (int j = 0; j < 4; ++j) {
                ssum[r][l][j] += ssum[r + off][l][j];
                ssq[r][l][j]  += ssq[r + off][l][j];
            }
        }
        __syncthreads();
    }
    if (r == 0) {
        float cnt = (float)max(e - s, 1);
#pragma unroll
        for (int j = 0; j < 4; ++j) {
            int c = c0 + j;
            float mean = ssum[0][l][j] / cnt;
            float m2   = ssq[0][l][j] / cnt;
            float msv  = ms[c];
            float var  = fmaxf(m2 - mean * mean * msv * (2.f - msv), 0.f);
            float a    = gw[c] * rsqrtf(var + EPS_GN);
            sA[l * 4 + j] = a;
            sS[l * 4 + j] = gb[c] - a * msv * mean;
        }
    }
    __syncthreads();
    float a0 = sA[l * 4], a1 = sA[l * 4 + 1], a2 = sA[l * 4 + 2], a3 = sA[l * 4 + 3];
    float h0 = sS[l * 4], h1 = sS[l * 4 + 1], h2 = sS[l * 4 + 2], h3 = sS[l * 4 + 3];
    for (int n = s + r; n < e; n += 32) {
        u16x4 v = *(const u16x4*)(tmp + (size_t)n * HIDDEN + c0);
        float4 o;
        o.x = fmaxf(fmaf(a0, b2f(v[0]), h0), 0.f);
        o.y = fmaxf(fmaf(a1, b2f(v[1]), h1), 0.f);
        o.z = fmaxf(fmaf(a2, b2f(v[2]), h2), 0.f);
        o.w = fmaxf(fmaf(a3, b2f(v[3]), h3), 0.f);
        *(float4*)(out + (size_t)n * HIDDEN + c0) = o;
    }
}

extern "C" void kernel_launch(void* const* d_in, const int* in_sizes, int n_in,
                              void* d_out, int out_size, void* d_ws, size_t ws_size,
                              hipStream_t stream) {
    const float* node  = (const float*)d_in[0];
    const int*   ei    = (const int*)d_in[1];
    const float* eattr = (const float*)d_in[2];
    const int*   batch = (const int*)d_in[3];
    const float* W     = (const float*)d_in[4];
    const float* b     = (const float*)d_in[5];
    const float* gnw   = (const float*)d_in[6];
    const float* gnb   = (const float*)d_in[7];
    const float* gnms  = (const float*)d_in[8];
    float* out = (float*)d_out;
    float* ws  = (float*)d_ws;

    const int* src = ei;
    const int* dst = ei + N_EDGES;

    unsigned short* hb = (unsigned short*)(ws + HB_OFF);
    u64*   cnt64   = (u64*)(ws + CNT64_OFF);
    float* dinv    = ws + DINV_OFF;
    unsigned short* wb = (unsigned short*)(ws + WB_OFF);
    int*   gstart  = (int*)(ws + GSTART_OFF);
    int*   rowstart= (int*)(ws + ROWS_OFF);
    int*   bsum    = (int*)(ws + BSUM_OFF);
    u64*   epack   = (u64*)(ws + EPACK_OFF);
    unsigned int* slot = (unsigned int*)(ws + SLOT_OFF);
    unsigned short* tmp = (unsigned short*)(ws + TMP_OFF);   // overlays slot (dead after csr_fill)

    prep<<<98, 256, 0, stream>>>(W, wb, (uint4*)cnt64);
    gemm_hist<<<NGEMM_BLK + NHIST_BLK, 256, 0, stream>>>(node, wb, hb, dst, eattr, cnt64, slot);
    scan_partial<<<NB_SCAN, 256, 0, stream>>>(cnt64, bsum, dinv, batch, gstart);
    scan_emit<<<NB_SCAN, 256, 0, stream>>>(cnt64, bsum, rowstart);
    csr_fill<<<(N_EDGES / 4 + 255) / 256, 256, 0, stream>>>(src, dst, eattr, dinv, rowstart, slot, epack);
    gather_fused<<<(N_NODES + 15) / 16, 256, 0, stream>>>(hb, rowstart, epack, dinv, b, tmp);
    stats_apply<<<NUM_GRAPHS * 4, 256, 0, stream>>>(tmp, gstart, gnms, gnw, gnb, out);

    (void)in_sizes; (void)n_in; (void)out_size; (void)ws_size;
}